// Round 16
// baseline (375.129 us; speedup 1.0000x reference)
//
#include <hip/hip_runtime.h>

#define BATCH 4096
#define SEQ   200
#define HID   128
#define ROWS  8     // valid batch rows per block (M=16 MFMA tile, rows 8-15 junk)
#define NTH   512

typedef _Float16 f16;
typedef f16 f16x4 __attribute__((ext_vector_type(4)));
typedef f16 f16x8 __attribute__((ext_vector_type(8)));
typedef float f32x4 __attribute__((ext_vector_type(4)));

#define MFMA(a, b, c) __builtin_amdgcn_mfma_f32_16x16x32_f16((a), (b), (c), 0, 0, 0)

__device__ __forceinline__ float fast_exp2(float x) {
#if defined(__has_builtin) && __has_builtin(__builtin_amdgcn_exp2f)
    return __builtin_amdgcn_exp2f(x);
#else
    float r; asm volatile("v_exp_f32 %0, %1\n\ts_nop 0" : "=v"(r) : "v"(x)); return r;
#endif
}
__device__ __forceinline__ float fast_rcp(float x) {
#if defined(__has_builtin) && __has_builtin(__builtin_amdgcn_rcpf)
    return __builtin_amdgcn_rcpf(x);
#else
    float r; asm volatile("v_rcp_f32 %0, %1\n\ts_nop 0" : "=v"(r) : "v"(x)); return r;
#endif
}
#define LOG2E  1.442695041f
#define LOG2E2 2.885390082f

// Persistent GRU, v10 = v9 with ROWS=8 / grid=512 -> TWO blocks per CU.
// Round 15 evidence: step budget 2640 cyc/CU vs ~500-1200 cyc of actual pipe
// work -> latency/lockstep-bound (8 waves behind one barrier, 2 waves/SIMD).
// Two independent blocks per CU interleave: one block's barrier drain is
// filled by the other block's compute. Price: M=16 tiles half-empty (MFMA
// issue x2, still ~35% of budget) and VALU x2 per CU (was 44% busy).
// Junk rows 8-15: A-frags stay zero (writes masked), gate results for hi>=2
// discarded, h/x/out writes masked -> write conflicts also halve.
__global__ __attribute__((amdgpu_flat_work_group_size(NTH, NTH)))
void gru_mfma(const int* __restrict__ inputs,
              const float* __restrict__ emb,
              const float* __restrict__ kernel,
              const float* __restrict__ rec_kernel,
              const float* __restrict__ bias,
              float* __restrict__ out)
{
    // fragment-linear tiles: flat f16 index ((buf_or_w*4 + kt)*64 + unit)*8 + e
    __shared__ __align__(16) f16 Wtf[8][4][64][8];   // rec h-gate, per-wave frags, 32 KB
    __shared__ __align__(16) f16 xf[2][4][64][8];    // x_t frags, dbuf, 8 KB
    __shared__ __align__(16) f16 hf[2][4][64][8];    // h_{t-1} frags, dbuf, 8 KB
    __shared__ int tok_sh[2][16];
    __shared__ int ts_sh;

    const int tid  = threadIdx.x;
    const int lane = tid & 63;
    const int wv   = tid >> 6;          // wave id 0..7
    const int j0   = wv * 16;           // wave's column slice
    const int l15  = lane & 15;
    const int hi   = lane >> 4;         // 0..3
    const int r0   = hi * 4;            // D-layout row base (valid if < ROWS)
    const int row0 = blockIdx.x * ROWS;

    // int32-vs-int64 token stride, detected from data (int64 LE: odd words 0)
    if (tid == 0) { int any = 0; for (int i = 1; i < 128; i += 2) any |= inputs[i]; ts_sh = any ? 1 : 2; }

    // --- stage rec_kernel h-gate into LDS in fragment order, pre-scaled ---
    for (int i = tid; i < 8 * 4 * 64 * 8; i += NTH) {
        const int e = i & 7, ln = (i >> 3) & 63, kt = (i >> 9) & 3, w = i >> 11;
        const int c = w * 16 + (ln & 15);
        const int k = kt * 32 + (ln >> 4) * 8 + e;
        ((f16*)Wtf)[i] = (f16)(LOG2E2 * rec_kernel[(size_t)k * 384 + 256 + c]);
    }

    // --- one-time register fragments (gate scales folded) ---
    f16x8 Bx[3][4];            // kernel: z,r scaled -LOG2E; h scaled +LOG2E2
    f16x8 Brz[4], Brr[4];      // rec_kernel z,r scaled -LOG2E
    const float gsc[3] = { -LOG2E, -LOG2E, LOG2E2 };
#pragma unroll
    for (int g = 0; g < 3; ++g)
#pragma unroll
        for (int kt = 0; kt < 4; ++kt) {
            f16x8 t;
#pragma unroll
            for (int e = 0; e < 8; ++e)
                t[e] = (f16)(gsc[g] * kernel[(size_t)(kt * 32 + hi * 8 + e) * 384 + g * HID + j0 + l15]);
            Bx[g][kt] = t;
        }
#pragma unroll
    for (int kt = 0; kt < 4; ++kt) {
        f16x8 tz, tr;
#pragma unroll
        for (int e = 0; e < 8; ++e) {
            const size_t krow = (size_t)(kt * 32 + hi * 8 + e) * 384;
            tz[e] = (f16)(-LOG2E * rec_kernel[krow + j0 + l15]);
            tr[e] = (f16)(-LOG2E * rec_kernel[krow + HID + j0 + l15]);
        }
        Brz[kt] = tz; Brr[kt] = tr;
    }

    // biases for this lane's column, same folding
    const float bz  = -LOG2E * (bias[j0 + l15]       + bias[384 + j0 + l15]);
    const float br  = -LOG2E * (bias[128 + j0 + l15] + bias[512 + j0 + l15]);
    const float bxh =  LOG2E2 * bias[256 + j0 + l15];
    const float brh =  LOG2E2 * bias[640 + j0 + l15];

    f32x4 h = {0.f, 0.f, 0.f, 0.f};     // h state: rows r0..r0+3, col j0+l15

    // h-write fragment address components (this lane's column c = j0+l15)
    const int cw  = j0 + l15;
    const int hwi = ((cw >> 5) * 64 + ((cw >> 3) & 3) * 16 + r0) * 8 + (cw & 7);  // + i*8 per row
    const bool vrow = (r0 < ROWS);      // this lane's D-rows are valid batch rows

    const int rr = tid >> 5;            // gather row 0..15 (active if < ROWS)
    const int c4 = (tid & 31) * 4;      // gather: 4 consecutive k
    const int xwi = ((c4 >> 5) * 64 + ((c4 >> 3) & 3) * 16 + rr) * 8 + (c4 & 7); // x-stage frag idx
    const bool act = (rr < ROWS);       // staging-active thread

    // --- prologue: zero hf (both bufs) + xf junk rows; init tok junk rows ---
    for (int i = tid; i < 2 * 4 * 64 * 8; i += NTH) {
        ((f16*)hf)[i] = (f16)0.f;                          // all h rows, both bufs
        if (((i >> 3) & 15) >= ROWS) ((f16*)xf)[i] = (f16)0.f;  // x junk rows only
    }
    if (tid < 16 && tid >= ROWS) { tok_sh[0][tid] = 1; tok_sh[1][tid] = 1; }
    __syncthreads();                    // ts_sh ready (also fences zeroing vs staging)
    const int ts = ts_sh;

    // --- stage x/tok for s=0 into buf 0 ---
    int tokA = 0;
    if (act) {
        const int tok0 = inputs[((size_t)(row0 + rr) * SEQ + 0) * ts];
        if ((tid & 31) == 0) tok_sh[0][rr] = tok0;
        const float4 ev = *(const float4*)&emb[(size_t)tok0 * HID + c4];
        f16x4 xv; xv[0] = (f16)ev.x; xv[1] = (f16)ev.y; xv[2] = (f16)ev.z; xv[3] = (f16)ev.w;
        *(f16x4*)&((f16*)xf)[xwi] = xv;                 // buf 0
        tokA = inputs[((size_t)(row0 + rr) * SEQ + 1) * ts];   // token for s+1
    }
    __syncthreads();

    for (int s = 0; s < SEQ; ++s) {
        const int cur = s & 1, nxt = cur ^ 1;
        const bool pf = (s + 1 < SEQ);
        float4 ev; int tokB = tokA;
        if (pf && act) {   // issue next-step gather early; lands in [nxt] after gates
            ev = *(const float4*)&emb[(size_t)tokA * HID + c4];
            const int s2 = (s + 2 < SEQ) ? (s + 2) : (SEQ - 1);
            tokB = inputs[((size_t)(row0 + rr) * SEQ + s2) * ts];
        }

        f32x4 az = {bz, bz, bz, bz}, ar = {br, br, br, br};
        f32x4 ax = {bxh, bxh, bxh, bxh}, ah = {brh, brh, brh, brh};
#pragma unroll
        for (int kt = 0; kt < 4; ++kt) {
            const f16x8 xa = *(const f16x8*)&xf[cur][kt][lane][0];
            const f16x8 ha = *(const f16x8*)&hf[cur][kt][lane][0];
            az = MFMA(xa, Bx[0][kt], az);
            ar = MFMA(xa, Bx[1][kt], ar);
            ax = MFMA(xa, Bx[2][kt], ax);
            az = MFMA(ha, Brz[kt], az);
            ar = MFMA(ha, Brr[kt], ar);
            const f16x8 rh = *(const f16x8*)&Wtf[wv][kt][lane][0];
            ah = MFMA(ha, rh, ah);
        }

        // gates — lane-local; scales pre-folded into the accumulators
#pragma unroll
        for (int i = 0; i < 4; ++i) {
            const int tk = tok_sh[cur][r0 + i];
            const float z  = fast_rcp(1.f + fast_exp2(az[i]));
            const float rg = fast_rcp(1.f + fast_exp2(ar[i]));
            const float u  = ax[i] + rg * ah[i];              // already 2*log2e-scaled
            const float hh = 1.f - 2.f * fast_rcp(1.f + fast_exp2(u));
            const float hn = hh + z * (h[i] - hh);
            h[i] = (tk != 0) ? hn : h[i];
        }

        // scatter h into fragment order for [nxt] — valid rows only
        if (vrow) {
            f16* hp = &((f16*)hf)[nxt * 4 * 64 * 8 + hwi];
#pragma unroll
            for (int i = 0; i < 4; ++i) hp[i * 8] = (f16)h[i];
        }
        if (pf && act) {
            f16x4 xv; xv[0] = (f16)ev.x; xv[1] = (f16)ev.y; xv[2] = (f16)ev.z; xv[3] = (f16)ev.w;
            *(f16x4*)&((f16*)xf)[nxt * 4 * 64 * 8 + xwi] = xv;
            if ((tid & 31) == 0) tok_sh[nxt][rr] = tokA;
            tokA = tokB;
        }
        __syncthreads();   // [nxt] ready; sole barrier per step
    }

    if (vrow) {
#pragma unroll
        for (int i = 0; i < 4; ++i)
            out[(size_t)(row0 + r0 + i) * HID + j0 + l15] = h[i];
    }
}

extern "C" void kernel_launch(void* const* d_in, const int* in_sizes, int n_in,
                              void* d_out, int out_size, void* d_ws, size_t ws_size,
                              hipStream_t stream) {
    const int* inputs      = (const int*)d_in[0];
    const float* emb       = (const float*)d_in[1];
    const float* kernel    = (const float*)d_in[2];
    const float* rec_k     = (const float*)d_in[3];
    const float* bias      = (const float*)d_in[4];
    float* out             = (float*)d_out;
    gru_mfma<<<BATCH / ROWS, NTH, 0, stream>>>(inputs, emb, kernel, rec_k, bias, out);
}

// Round 21
// 260.835 us; speedup vs baseline: 1.4382x; 1.4382x over previous
//
#include <hip/hip_runtime.h>

#define BATCH 4096
#define SEQ   200
#define HID   128
#define ROWS  16
#define NTH   512

typedef _Float16 f16;
typedef f16 f16x4 __attribute__((ext_vector_type(4)));
typedef f16 f16x8 __attribute__((ext_vector_type(8)));
typedef float f32x4 __attribute__((ext_vector_type(4)));

#define MFMA(a, b, c) __builtin_amdgcn_mfma_f32_16x16x32_f16((a), (b), (c), 0, 0, 0)

__device__ __forceinline__ float fast_exp2(float x) {
#if defined(__has_builtin) && __has_builtin(__builtin_amdgcn_exp2f)
    return __builtin_amdgcn_exp2f(x);
#else
    float r; asm volatile("v_exp_f32 %0, %1\n\ts_nop 0" : "=v"(r) : "v"(x)); return r;
#endif
}
__device__ __forceinline__ float fast_rcp(float x) {
#if defined(__has_builtin) && __has_builtin(__builtin_amdgcn_rcpf)
    return __builtin_amdgcn_rcpf(x);
#else
    float r; asm volatile("v_rcp_f32 %0, %1\n\ts_nop 0" : "=v"(r) : "v"(x)); return r;
#endif
}
#define LOG2E  1.442695041f
#define LOG2E2 2.885390082f

// Persistent GRU, v12 = v9 + TWO-TILE ILP. Round 16 falsified 2-block
// co-residency (occupancy stuck at 23%, serial 2x); round 15 showed one
// block is lockstep-stalled (2640 cyc/step vs ~700 cyc pipe work). Fix
// INSIDE the block: split the 16 batch rows into two independent M=16
// tiles (P: rows 0-7 in frag rows 0-7; Q: rows 8-15 in frag rows 8-15;
// junk A rows only produce junk D rows -> discarded). Two independent
// MFMA/gate chains per step fill each other's stall bubbles. Weights
// shared between tiles (no extra weight regs; +16 acc regs). Gates:
// P-lanes (hi<2) select accP, Q-lanes accQ -> every lane does one gate's
// work; out-row formula unchanged (lane owns rows r0..r0+3).
__global__ __attribute__((amdgpu_flat_work_group_size(NTH, NTH)))
void gru_mfma(const int* __restrict__ inputs,
              const float* __restrict__ emb,
              const float* __restrict__ kernel,
              const float* __restrict__ rec_kernel,
              const float* __restrict__ bias,
              float* __restrict__ out)
{
    // fragment-linear tiles: f16 idx within array: ((buf*4 + kt)*64 + unit)*8 + e
    __shared__ __align__(16) f16 Wtf[8][4][64][8];    // rec h-gate frags, 32 KB (shared by P,Q)
    __shared__ __align__(16) f16 xfP[2][4][64][8];    // x frags tile P (rows 0-7 valid)
    __shared__ __align__(16) f16 xfQ[2][4][64][8];    // x frags tile Q (rows 8-15 valid)
    __shared__ __align__(16) f16 hfP[2][4][64][8];    // h frags tile P
    __shared__ __align__(16) f16 hfQ[2][4][64][8];    // h frags tile Q
    __shared__ int tok_sh[2][ROWS];
    __shared__ int ts_sh;

    const int tid  = threadIdx.x;
    const int lane = tid & 63;
    const int wv   = tid >> 6;          // wave id 0..7
    const int j0   = wv * 16;           // wave's column slice
    const int l15  = lane & 15;
    const int hi   = lane >> 4;         // 0..3
    const int r0   = hi * 4;            // D-layout row base (0..15)
    const int row0 = blockIdx.x * ROWS;

    // int32-vs-int64 token stride, detected from data (int64 LE: odd words 0)
    if (tid == 0) { int any = 0; for (int i = 1; i < 128; i += 2) any |= inputs[i]; ts_sh = any ? 1 : 2; }

    // --- stage rec_kernel h-gate into LDS in fragment order, pre-scaled ---
    for (int i = tid; i < 8 * 4 * 64 * 8; i += NTH) {
        const int e = i & 7, ln = (i >> 3) & 63, kt = (i >> 9) & 3, w = i >> 11;
        const int c = w * 16 + (ln & 15);
        const int k = kt * 32 + (ln >> 4) * 8 + e;
        ((f16*)Wtf)[i] = (f16)(LOG2E2 * rec_kernel[(size_t)k * 384 + 256 + c]);
    }

    // --- one-time register fragments (gate scales folded) ---
    f16x8 Bx[3][4];            // kernel: z,r scaled -LOG2E; h scaled +LOG2E2
    f16x8 Brz[4], Brr[4];      // rec_kernel z,r scaled -LOG2E
    const float gsc[3] = { -LOG2E, -LOG2E, LOG2E2 };
#pragma unroll
    for (int g = 0; g < 3; ++g)
#pragma unroll
        for (int kt = 0; kt < 4; ++kt) {
            f16x8 t;
#pragma unroll
            for (int e = 0; e < 8; ++e)
                t[e] = (f16)(gsc[g] * kernel[(size_t)(kt * 32 + hi * 8 + e) * 384 + g * HID + j0 + l15]);
            Bx[g][kt] = t;
        }
#pragma unroll
    for (int kt = 0; kt < 4; ++kt) {
        f16x8 tz, tr;
#pragma unroll
        for (int e = 0; e < 8; ++e) {
            const size_t krow = (size_t)(kt * 32 + hi * 8 + e) * 384;
            tz[e] = (f16)(-LOG2E * rec_kernel[krow + j0 + l15]);
            tr[e] = (f16)(-LOG2E * rec_kernel[krow + HID + j0 + l15]);
        }
        Brz[kt] = tz; Brr[kt] = tr;
    }

    // biases for this lane's column, scales folded (same for both tiles)
    const float bz  = -LOG2E * (bias[j0 + l15]       + bias[384 + j0 + l15]);
    const float br  = -LOG2E * (bias[128 + j0 + l15] + bias[512 + j0 + l15]);
    const float bxh =  LOG2E2 * bias[256 + j0 + l15];
    const float brh =  LOG2E2 * bias[640 + j0 + l15];

    f32x4 h = {0.f, 0.f, 0.f, 0.f};     // h state: this lane's tile rows r0..r0+3

    // h-write fragment address (column c = j0+l15, rows r0..r0+3) — tile base selected below
    const int cw  = j0 + l15;
    const int hwi = ((cw >> 5) * 64 + ((cw >> 3) & 3) * 16 + r0) * 8 + (cw & 7);  // + i*8
    f16* const hfbase = (hi < 2) ? (f16*)hfP : (f16*)hfQ;

    const int rr = tid >> 5;            // stage row 0..15
    const int c4 = (tid & 31) * 4;      // stage: 4 consecutive k
    const int xwi = ((c4 >> 5) * 64 + ((c4 >> 3) & 3) * 16 + rr) * 8 + (c4 & 7);
    f16* const xfbase = (rr < 8) ? (f16*)xfP : (f16*)xfQ;

    // --- zero h frags (both tiles/bufs) + x JUNK units only (no race w/ stage) ---
    for (int i = tid; i < 2 * 4 * 64 * 8; i += NTH) {
        ((f16*)hfP)[i] = (f16)0.f; ((f16*)hfQ)[i] = (f16)0.f;
        const int u15 = (i >> 3) & 15;
        if (u15 >= 8) ((f16*)xfP)[i] = (f16)0.f;
        if (u15 <  8) ((f16*)xfQ)[i] = (f16)0.f;
    }
    __syncthreads();                    // ts_sh/Wtf/zero done
    const int ts = ts_sh;

    // --- stage x/tok for s=0 into buf 0 ---
    {
        const int tok0 = inputs[((size_t)(row0 + rr) * SEQ + 0) * ts];
        if ((tid & 31) == 0) tok_sh[0][rr] = tok0;
        const float4 ev = *(const float4*)&emb[(size_t)tok0 * HID + c4];
        f16x4 xv; xv[0] = (f16)ev.x; xv[1] = (f16)ev.y; xv[2] = (f16)ev.z; xv[3] = (f16)ev.w;
        *(f16x4*)&xfbase[xwi] = xv;     // buf 0
    }
    int tokA = inputs[((size_t)(row0 + rr) * SEQ + 1) * ts];   // token for s+1
    __syncthreads();

    for (int s = 0; s < SEQ; ++s) {
        const int cur = s & 1, nxt = cur ^ 1;
        const bool pf = (s + 1 < SEQ);
        float4 ev; int tokB = tokA;
        if (pf) {   // issue next-step gather early; lands in [nxt] after gates
            ev = *(const float4*)&emb[(size_t)tokA * HID + c4];
            const int s2 = (s + 2 < SEQ) ? (s + 2) : (SEQ - 1);
            tokB = inputs[((size_t)(row0 + rr) * SEQ + s2) * ts];
        }

        f32x4 azP = {bz,bz,bz,bz}, arP = {br,br,br,br}, axP = {bxh,bxh,bxh,bxh}, ahP = {brh,brh,brh,brh};
        f32x4 azQ = {bz,bz,bz,bz}, arQ = {br,br,br,br}, axQ = {bxh,bxh,bxh,bxh}, ahQ = {brh,brh,brh,brh};
#pragma unroll
        for (int kt = 0; kt < 4; ++kt) {
            const f16x8 xaP = *(const f16x8*)&xfP[cur][kt][lane][0];
            const f16x8 haP = *(const f16x8*)&hfP[cur][kt][lane][0];
            const f16x8 xaQ = *(const f16x8*)&xfQ[cur][kt][lane][0];
            const f16x8 haQ = *(const f16x8*)&hfQ[cur][kt][lane][0];
            const f16x8 rh  = *(const f16x8*)&Wtf[wv][kt][lane][0];
            azP = MFMA(xaP, Bx[0][kt], azP); arP = MFMA(xaP, Bx[1][kt], arP); axP = MFMA(xaP, Bx[2][kt], axP);
            azP = MFMA(haP, Brz[kt], azP);   arP = MFMA(haP, Brr[kt], arP);   ahP = MFMA(haP, rh, ahP);
            azQ = MFMA(xaQ, Bx[0][kt], azQ); arQ = MFMA(xaQ, Bx[1][kt], arQ); axQ = MFMA(xaQ, Bx[2][kt], axQ);
            azQ = MFMA(haQ, Brz[kt], azQ);   arQ = MFMA(haQ, Brr[kt], arQ);   ahQ = MFMA(haQ, rh, ahQ);
        }

        // gates — each lane handles its OWN tile's rows r0..r0+3
        const bool qsel = (hi >= 2);
        const f32x4 az = qsel ? azQ : azP;
        const f32x4 ar = qsel ? arQ : arP;
        const f32x4 ax = qsel ? axQ : axP;
        const f32x4 ah = qsel ? ahQ : ahP;
#pragma unroll
        for (int i = 0; i < 4; ++i) {
            const int tk = tok_sh[cur][r0 + i];
            const float z  = fast_rcp(1.f + fast_exp2(az[i]));
            const float rg = fast_rcp(1.f + fast_exp2(ar[i]));
            const float u  = ax[i] + rg * ah[i];              // already 2*log2e-scaled
            const float hh = 1.f - 2.f * fast_rcp(1.f + fast_exp2(u));
            const float hn = hh + z * (h[i] - hh);
            h[i] = (tk != 0) ? hn : h[i];
        }

        // scatter h into own tile's frag buffer [nxt]
        {
            f16* hp = hfbase + nxt * (4 * 64 * 8) + hwi;
#pragma unroll
            for (int i = 0; i < 4; ++i) hp[i * 8] = (f16)h[i];
        }
        if (pf) {
            f16x4 xv; xv[0] = (f16)ev.x; xv[1] = (f16)ev.y; xv[2] = (f16)ev.z; xv[3] = (f16)ev.w;
            *(f16x4*)&xfbase[nxt * (4 * 64 * 8) + xwi] = xv;
            if ((tid & 31) == 0) tok_sh[nxt][rr] = tokA;
            tokA = tokB;
        }
        __syncthreads();   // [nxt] ready; sole barrier per step
    }

#pragma unroll
    for (int i = 0; i < 4; ++i)
        out[(size_t)(row0 + r0 + i) * HID + j0 + l15] = h[i];
}

extern "C" void kernel_launch(void* const* d_in, const int* in_sizes, int n_in,
                              void* d_out, int out_size, void* d_ws, size_t ws_size,
                              hipStream_t stream) {
    const int* inputs      = (const int*)d_in[0];
    const float* emb       = (const float*)d_in[1];
    const float* kernel    = (const float*)d_in[2];
    const float* rec_k     = (const float*)d_in[3];
    const float* bias      = (const float*)d_in[4];
    float* out             = (float*)d_out;
    gru_mfma<<<BATCH / ROWS, NTH, 0, stream>>>(inputs, emb, kernel, rec_k, bias, out);
}

// Round 22
// 176.354 us; speedup vs baseline: 2.1271x; 1.4790x over previous
//
#include <hip/hip_runtime.h>

#define BATCH 4096
#define SEQ   200
#define HID   128
#define ROWS  16
#define NTH   512

typedef _Float16 f16;
typedef f16 f16x4 __attribute__((ext_vector_type(4)));
typedef f16 f16x8 __attribute__((ext_vector_type(8)));
typedef float f32x4 __attribute__((ext_vector_type(4)));
typedef int   i32x4 __attribute__((ext_vector_type(4)));

#define MFMA(a, b, c) __builtin_amdgcn_mfma_f32_16x16x32_f16((a), (b), (c), 0, 0, 0)

__device__ __forceinline__ float fast_exp2(float x) {
#if defined(__has_builtin) && __has_builtin(__builtin_amdgcn_exp2f)
    return __builtin_amdgcn_exp2f(x);
#else
    float r; asm volatile("v_exp_f32 %0, %1\n\ts_nop 0" : "=v"(r) : "v"(x)); return r;
#endif
}
__device__ __forceinline__ float fast_rcp(float x) {
#if defined(__has_builtin) && __has_builtin(__builtin_amdgcn_rcpf)
    return __builtin_amdgcn_rcpf(x);
#else
    float r; asm volatile("v_rcp_f32 %0, %1\n\ts_nop 0" : "=v"(r) : "v"(x)); return r;
#endif
}
#define LOG2E  1.442695041f
#define LOG2E2 2.885390082f

// Persistent GRU, v13 = v9 (182us, best) + three chain-shortening changes.
// Round 21 falsified two-tile ILP (MFMA work doubled serially, 316us) and
// confirmed occupancy is register-capped at 8 waves/CU — so the fix must
// shorten the single chain, not widen it:
//  1) ALL weights register-resident: rec-h frags (Brh, +16 regs) join z/r;
//     Wtf LDS dropped (−4 ds_read_b128/wave-step, LDS 49.6->17 KB). gfx950
//     unified RF: weight frags may live in AGPRs, still direct MFMA operands.
//  2) Split accumulators per projection: 6 independent 4-deep MFMA chains
//     (azx/azh, arx/arh, ax, ah) instead of two 8-deep ones.
//  3) Gate tokens read as one int4 ds_read per lane at step top.
// grid 256 x 512thr: block = 16 batch rows; wave w = cols [16w,16w+16).
// Gates lane-local in D layout (col=lane&15, row=(lane>>4)*4+reg, m89).
__global__ __attribute__((amdgpu_flat_work_group_size(NTH, NTH)))
void gru_mfma(const int* __restrict__ inputs,
              const float* __restrict__ emb,
              const float* __restrict__ kernel,
              const float* __restrict__ rec_kernel,
              const float* __restrict__ bias,
              float* __restrict__ out)
{
    // fragment-linear tiles: f16 idx: ((buf*4 + kt)*64 + unit)*8 + e
    __shared__ __align__(16) f16 xf[2][4][64][8];    // x_t frags, dbuf, 8 KB
    __shared__ __align__(16) f16 hf[2][4][64][8];    // h_{t-1} frags, dbuf, 8 KB
    __shared__ __align__(16) int tok_sh[2][ROWS];
    __shared__ int ts_sh;

    const int tid  = threadIdx.x;
    const int lane = tid & 63;
    const int j0   = (tid >> 6) * 16;   // wave's column slice
    const int l15  = lane & 15;
    const int hi   = lane >> 4;         // 0..3
    const int r0   = hi * 4;            // D-layout row base
    const int row0 = blockIdx.x * ROWS;

    // int32-vs-int64 token stride, detected from data (int64 LE: odd words 0)
    if (tid == 0) { int any = 0; for (int i = 1; i < 128; i += 2) any |= inputs[i]; ts_sh = any ? 1 : 2; }

    // --- one-time register fragments (gate scales folded) ---
    f16x8 Bx[3][4];                 // kernel: z,r scaled -LOG2E; h scaled +LOG2E2
    f16x8 Brz[4], Brr[4], Brh[4];   // rec_kernel: z,r scaled -LOG2E; h scaled +LOG2E2
    const float gsc[3] = { -LOG2E, -LOG2E, LOG2E2 };
#pragma unroll
    for (int g = 0; g < 3; ++g)
#pragma unroll
        for (int kt = 0; kt < 4; ++kt) {
            f16x8 t;
#pragma unroll
            for (int e = 0; e < 8; ++e)
                t[e] = (f16)(gsc[g] * kernel[(size_t)(kt * 32 + hi * 8 + e) * 384 + g * HID + j0 + l15]);
            Bx[g][kt] = t;
        }
#pragma unroll
    for (int kt = 0; kt < 4; ++kt) {
        f16x8 tz, tr, th;
#pragma unroll
        for (int e = 0; e < 8; ++e) {
            const size_t krow = (size_t)(kt * 32 + hi * 8 + e) * 384;
            tz[e] = (f16)(-LOG2E  * rec_kernel[krow + j0 + l15]);
            tr[e] = (f16)(-LOG2E  * rec_kernel[krow + HID + j0 + l15]);
            th[e] = (f16)(LOG2E2 * rec_kernel[krow + 2 * HID + j0 + l15]);
        }
        Brz[kt] = tz; Brr[kt] = tr; Brh[kt] = th;
    }

    // biases for this lane's column, scales folded
    const float bz  = -LOG2E * (bias[j0 + l15]       + bias[384 + j0 + l15]);
    const float br  = -LOG2E * (bias[128 + j0 + l15] + bias[512 + j0 + l15]);
    const float bxh =  LOG2E2 * bias[256 + j0 + l15];
    const float brh =  LOG2E2 * bias[640 + j0 + l15];

    f32x4 h = {0.f, 0.f, 0.f, 0.f};     // h state: rows r0..r0+3, col j0+l15

    // h-write fragment address (column c = j0+l15, rows r0..r0+3)
    const int cw  = j0 + l15;
    const int hwi = ((cw >> 5) * 64 + ((cw >> 3) & 3) * 16 + r0) * 8 + (cw & 7);  // + i*8

    const int rr = tid >> 5;            // stage: row 0..15
    const int c4 = (tid & 31) * 4;      // stage: 4 consecutive k
    const int xwi = ((c4 >> 5) * 64 + ((c4 >> 3) & 3) * 16 + rr) * 8 + (c4 & 7);

    // --- zero hf[0] (scatter fully covers hf[1] during step 0) ---
    for (int i = tid; i < 4 * 64 * 8; i += NTH) ((f16*)hf)[i] = (f16)0.f;
    __syncthreads();                    // ts_sh + zero done
    const int ts = ts_sh;

    // --- stage x/tok for s=0 into buf 0 ---
    {
        const int tok0 = inputs[((size_t)(row0 + rr) * SEQ + 0) * ts];
        if ((tid & 31) == 0) tok_sh[0][rr] = tok0;
        const float4 ev = *(const float4*)&emb[(size_t)tok0 * HID + c4];
        f16x4 xv; xv[0] = (f16)ev.x; xv[1] = (f16)ev.y; xv[2] = (f16)ev.z; xv[3] = (f16)ev.w;
        *(f16x4*)&((f16*)xf)[xwi] = xv;     // buf 0
    }
    int tokA = inputs[((size_t)(row0 + rr) * SEQ + 1) * ts];   // token for s+1
    __syncthreads();

    for (int s = 0; s < SEQ; ++s) {
        const int cur = s & 1, nxt = cur ^ 1;
        const bool pf = (s + 1 < SEQ);
        float4 ev; int tokB = tokA;
        if (pf) {   // issue next-step gather early; lands in [nxt] after gates
            ev = *(const float4*)&emb[(size_t)tokA * HID + c4];
            const int s2 = (s + 2 < SEQ) ? (s + 2) : (SEQ - 1);
            tokB = inputs[((size_t)(row0 + rr) * SEQ + s2) * ts];
        }

        // tokens for this step's gates: one b128 read (broadcast per hi-group)
        const i32x4 tk = *(const i32x4*)&tok_sh[cur][r0];

        // 6 independent 4-deep MFMA chains
        f32x4 azx = {bz, bz, bz, bz},     arx = {br, br, br, br};
        f32x4 ax  = {bxh, bxh, bxh, bxh};
        f32x4 azh = {0.f, 0.f, 0.f, 0.f}, arh = {0.f, 0.f, 0.f, 0.f};
        f32x4 ah  = {brh, brh, brh, brh};
#pragma unroll
        for (int kt = 0; kt < 4; ++kt) {
            const f16x8 xa = *(const f16x8*)&xf[cur][kt][lane][0];
            const f16x8 ha = *(const f16x8*)&hf[cur][kt][lane][0];
            azx = MFMA(xa, Bx[0][kt], azx);
            arx = MFMA(xa, Bx[1][kt], arx);
            ax  = MFMA(xa, Bx[2][kt], ax);
            azh = MFMA(ha, Brz[kt], azh);
            arh = MFMA(ha, Brr[kt], arh);
            ah  = MFMA(ha, Brh[kt], ah);
        }

        // gates — lane-local; scales pre-folded
#pragma unroll
        for (int i = 0; i < 4; ++i) {
            const float z  = fast_rcp(1.f + fast_exp2(azx[i] + azh[i]));
            const float rg = fast_rcp(1.f + fast_exp2(arx[i] + arh[i]));
            const float u  = ax[i] + rg * ah[i];              // 2*log2e-scaled
            const float hh = 1.f - 2.f * fast_rcp(1.f + fast_exp2(u));
            const float hn = hh + z * (h[i] - hh);
            h[i] = (tk[i] != 0) ? hn : h[i];
        }

        // scatter h into fragment order for [nxt]
        {
            f16* hp = &((f16*)hf)[nxt * (4 * 64 * 8) + hwi];
#pragma unroll
            for (int i = 0; i < 4; ++i) hp[i * 8] = (f16)h[i];
        }
        if (pf) {
            f16x4 xv; xv[0] = (f16)ev.x; xv[1] = (f16)ev.y; xv[2] = (f16)ev.z; xv[3] = (f16)ev.w;
            *(f16x4*)&((f16*)xf)[nxt * (4 * 64 * 8) + xwi] = xv;
            if ((tid & 31) == 0) tok_sh[nxt][rr] = tokA;
            tokA = tokB;
        }
        __syncthreads();   // [nxt] ready; sole barrier per step
    }

#pragma unroll
    for (int i = 0; i < 4; ++i)
        out[(size_t)(row0 + r0 + i) * HID + j0 + l15] = h[i];
}

extern "C" void kernel_launch(void* const* d_in, const int* in_sizes, int n_in,
                              void* d_out, int out_size, void* d_ws, size_t ws_size,
                              hipStream_t stream) {
    const int* inputs      = (const int*)d_in[0];
    const float* emb       = (const float*)d_in[1];
    const float* kernel    = (const float*)d_in[2];
    const float* rec_k     = (const float*)d_in[3];
    const float* bias      = (const float*)d_in[4];
    float* out             = (float*)d_out;
    gru_mfma<<<BATCH / ROWS, NTH, 0, stream>>>(inputs, emb, kernel, rec_k, bias, out);
}

// Round 23
// 173.070 us; speedup vs baseline: 2.1675x; 1.0190x over previous
//
#include <hip/hip_runtime.h>

#define BATCH 4096
#define SEQ   200
#define HID   128
#define ROWS  16
#define NTH   512

typedef _Float16 f16;
typedef f16 f16x4 __attribute__((ext_vector_type(4)));
typedef f16 f16x8 __attribute__((ext_vector_type(8)));
typedef float f32x4 __attribute__((ext_vector_type(4)));

#define MFMA(a, b, c) __builtin_amdgcn_mfma_f32_16x16x32_f16((a), (b), (c), 0, 0, 0)

__device__ __forceinline__ float fast_exp2(float x) {
#if defined(__has_builtin) && __has_builtin(__builtin_amdgcn_exp2f)
    return __builtin_amdgcn_exp2f(x);
#else
    float r; asm volatile("v_exp_f32 %0, %1\n\ts_nop 0" : "=v"(r) : "v"(x)); return r;
#endif
}
__device__ __forceinline__ float fast_rcp(float x) {
#if defined(__has_builtin) && __has_builtin(__builtin_amdgcn_rcpf)
    return __builtin_amdgcn_rcpf(x);
#else
    float r; asm volatile("v_rcp_f32 %0, %1\n\ts_nop 0" : "=v"(r) : "v"(x)); return r;
#endif
}
#define LOG2E  1.442695041f
#define LOG2E2 2.885390082f

// Persistent GRU, v14 = v13 TRANSPOSED dataflow. Round 22: conflicts stayed
// exactly 1.475e7 after removing all Wtf READS -> the conflicts live in the
// strided b16 h-scatter/x-stage WRITES, and scatter packing is VALU mass.
// Transpose: weights = A operand (SAME registers as v13's B frags — A/B lane
// layouts are symmetric, so swap the MFMA arg order), x/h = B operand.
// D[row=out_col][col=batch]: lane holds batch=l15, out_cols j0+r0..+3
// CONSECUTIVE in hid ->
//   h-scatter = ONE ds_write_b64/lane (was 4 strided b16; 2-way = free),
//   out = ONE global_store_dwordx4 (was 4 dword),
//   token = 1 read + 1 cmp (was 4).
// B-frag staging: element (batch, hid) at [kt=hid/32][unit=((hid%32)/8)*16
// + batch][e=hid%8]; lane l reads its frag at [kt][l][0..7] contiguous ->
// reads stay conflict-free. Biases now vary per-reg-i (f32x4 per lane).
// grid 256 x 512thr; 6 independent 4-deep MFMA chains; 1 barrier/step.
__global__ __attribute__((amdgpu_flat_work_group_size(NTH, NTH)))
void gru_mfma(const int* __restrict__ inputs,
              const float* __restrict__ emb,
              const float* __restrict__ kernel,
              const float* __restrict__ rec_kernel,
              const float* __restrict__ bias,
              float* __restrict__ out)
{
    // B-operand fragment buffers: f16 idx ((buf*4 + kt)*64 + unit)*8 + e
    __shared__ __align__(16) f16 xb[2][4][64][8];    // x^T frags, dbuf, 8 KB
    __shared__ __align__(16) f16 hb[2][4][64][8];    // h^T frags, dbuf, 8 KB
    __shared__ int tok_sh[2][ROWS];
    __shared__ int ts_sh;

    const int tid  = threadIdx.x;
    const int lane = tid & 63;
    const int j0   = (tid >> 6) * 16;   // wave's hid-column slice
    const int l15  = lane & 15;         // batch index within tile
    const int hi   = lane >> 4;         // 0..3
    const int r0   = hi * 4;            // D row base -> out_col = j0+r0+i
    const int row0 = blockIdx.x * ROWS;

    // int32-vs-int64 token stride, detected from data (int64 LE: odd words 0)
    if (tid == 0) { int any = 0; for (int i = 1; i < 128; i += 2) any |= inputs[i]; ts_sh = any ? 1 : 2; }

    // --- one-time weight fragments (gate scales folded) — same layout as v13;
    // used as the A operand (arg 0) so they read as W^T ---
    f16x8 Bx[3][4];                 // kernel: z,r scaled -LOG2E; h scaled +LOG2E2
    f16x8 Brz[4], Brr[4], Brh[4];   // rec_kernel, same scaling
    const float gsc[3] = { -LOG2E, -LOG2E, LOG2E2 };
#pragma unroll
    for (int g = 0; g < 3; ++g)
#pragma unroll
        for (int kt = 0; kt < 4; ++kt) {
            f16x8 t;
#pragma unroll
            for (int e = 0; e < 8; ++e)
                t[e] = (f16)(gsc[g] * kernel[(size_t)(kt * 32 + hi * 8 + e) * 384 + g * HID + j0 + l15]);
            Bx[g][kt] = t;
        }
#pragma unroll
    for (int kt = 0; kt < 4; ++kt) {
        f16x8 tz, tr, th;
#pragma unroll
        for (int e = 0; e < 8; ++e) {
            const size_t krow = (size_t)(kt * 32 + hi * 8 + e) * 384;
            tz[e] = (f16)(-LOG2E  * rec_kernel[krow + j0 + l15]);
            tr[e] = (f16)(-LOG2E  * rec_kernel[krow + HID + j0 + l15]);
            th[e] = (f16)(LOG2E2 * rec_kernel[krow + 2 * HID + j0 + l15]);
        }
        Brz[kt] = tz; Brr[kt] = tr; Brh[kt] = th;
    }

    // biases for this lane's out_cols j0+r0+i (vary with i, not l15)
    f32x4 bzv, brv, bxhv, brhv;
#pragma unroll
    for (int i = 0; i < 4; ++i) {
        const int c = j0 + r0 + i;
        bzv[i]  = -LOG2E * (bias[c]       + bias[384 + c]);
        brv[i]  = -LOG2E * (bias[128 + c] + bias[512 + c]);
        bxhv[i] =  LOG2E2 * bias[256 + c];
        brhv[i] =  LOG2E2 * bias[640 + c];
    }

    f32x4 h = {0.f, 0.f, 0.f, 0.f};     // h[batch=l15][j0+r0+i]

    // h-scatter dest: hid = j0+r0 (e = (j0+r0)&7 = 4*(hi&1)), batch = l15
    const int hk  = j0 + r0;
    const int hwi = (((hk >> 5) * 64) + (((hk & 31) >> 3) * 16) + l15) * 8 + (hk & 7);

    const int rr = tid >> 5;            // stage: batch row 0..15
    const int c4 = (tid & 31) * 4;      // stage: 4 consecutive hid
    const int xwi = (((c4 >> 5) * 64) + (((c4 & 31) >> 3) * 16) + rr) * 8 + (c4 & 7);

    // --- zero hb[0] (step-0 scatter fully covers hb[1]) ---
    for (int i = tid; i < 4 * 64 * 8; i += NTH) ((f16*)hb)[i] = (f16)0.f;
    __syncthreads();                    // ts_sh + zero done
    const int ts = ts_sh;

    // --- stage x/tok for s=0 into buf 0 ---
    {
        const int tok0 = inputs[((size_t)(row0 + rr) * SEQ + 0) * ts];
        if ((tid & 31) == 0) tok_sh[0][rr] = tok0;
        const float4 ev = *(const float4*)&emb[(size_t)tok0 * HID + c4];
        f16x4 xv; xv[0] = (f16)ev.x; xv[1] = (f16)ev.y; xv[2] = (f16)ev.z; xv[3] = (f16)ev.w;
        *(f16x4*)&((f16*)xb)[xwi] = xv;     // buf 0
    }
    int tokA = inputs[((size_t)(row0 + rr) * SEQ + 1) * ts];   // token for s+1
    __syncthreads();

    for (int s = 0; s < SEQ; ++s) {
        const int cur = s & 1, nxt = cur ^ 1;
        const bool pf = (s + 1 < SEQ);
        float4 ev; int tokB = tokA;
        if (pf) {   // issue next-step gather early; lands in [nxt] after gates
            ev = *(const float4*)&emb[(size_t)tokA * HID + c4];
            const int s2 = (s + 2 < SEQ) ? (s + 2) : (SEQ - 1);
            tokB = inputs[((size_t)(row0 + rr) * SEQ + s2) * ts];
        }

        const int tkk = tok_sh[cur][l15];   // this lane's batch row token

        // 6 independent 4-deep MFMA chains (A = weights, B = x^T/h^T)
        f32x4 azx = bzv, arx = brv, ax = bxhv;
        f32x4 azh = {0.f, 0.f, 0.f, 0.f}, arh = {0.f, 0.f, 0.f, 0.f};
        f32x4 ah  = brhv;
#pragma unroll
        for (int kt = 0; kt < 4; ++kt) {
            const f16x8 xB = *(const f16x8*)&xb[cur][kt][lane][0];
            const f16x8 hB = *(const f16x8*)&hb[cur][kt][lane][0];
            azx = MFMA(Bx[0][kt], xB, azx);
            arx = MFMA(Bx[1][kt], xB, arx);
            ax  = MFMA(Bx[2][kt], xB, ax);
            azh = MFMA(Brz[kt], hB, azh);
            arh = MFMA(Brr[kt], hB, arh);
            ah  = MFMA(Brh[kt], hB, ah);
        }

        // gates — lane-local (batch l15, out_cols j0+r0+i)
        f16x4 hv;
#pragma unroll
        for (int i = 0; i < 4; ++i) {
            const float z  = fast_rcp(1.f + fast_exp2(azx[i] + azh[i]));
            const float rg = fast_rcp(1.f + fast_exp2(arx[i] + arh[i]));
            const float u  = ax[i] + rg * ah[i];              // 2*log2e-scaled
            const float hh = 1.f - 2.f * fast_rcp(1.f + fast_exp2(u));
            const float hn = hh + z * (h[i] - hh);
            h[i] = (tkk != 0) ? hn : h[i];
            hv[i] = (f16)h[i];
        }

        // scatter h^T frag: ONE b64 write (consecutive e), 2-way banks = free
        *(f16x4*)&((f16*)hb)[nxt * (4 * 64 * 8) + hwi] = hv;
        if (pf) {
            f16x4 xv; xv[0] = (f16)ev.x; xv[1] = (f16)ev.y; xv[2] = (f16)ev.z; xv[3] = (f16)ev.w;
            *(f16x4*)&((f16*)xb)[nxt * (4 * 64 * 8) + xwi] = xv;
            if ((tid & 31) == 0) tok_sh[nxt][rr] = tokA;
            tokA = tokB;
        }
        __syncthreads();   // [nxt] ready; sole barrier per step
    }

    // out: 4 consecutive hid cols for batch l15 -> one dwordx4
    float4 o; o.x = h[0]; o.y = h[1]; o.z = h[2]; o.w = h[3];
    *(float4*)&out[(size_t)(row0 + l15) * HID + j0 + r0] = o;
}

extern "C" void kernel_launch(void* const* d_in, const int* in_sizes, int n_in,
                              void* d_out, int out_size, void* d_ws, size_t ws_size,
                              hipStream_t stream) {
    const int* inputs      = (const int*)d_in[0];
    const float* emb       = (const float*)d_in[1];
    const float* kernel    = (const float*)d_in[2];
    const float* rec_k     = (const float*)d_in[3];
    const float* bias      = (const float*)d_in[4];
    float* out             = (float*)d_out;
    gru_mfma<<<BATCH / ROWS, NTH, 0, stream>>>(inputs, emb, kernel, rec_k, bias, out);
}